// Round 3
// baseline (102.379 us; speedup 1.0000x reference)
//
#include <hip/hip_runtime.h>
#include <hip/hip_fp16.h>
#include <stdint.h>

#define H_ 120
#define W_ 160
#define HW_ (H_*W_)          // 19200
#define SKIP_ 8
#define P_ (HW_/SKIP_)       // 2400 voting pixels
#define NC_ 8                // classes
#define CAP_ 320             // per-class segment capacity (mult of 32; expected ~150/class, +14 sigma safe)
#define PADCAP_ (NC_*CAP_)   // 2560 -> 40960 B LDS -> 3 blocks/CU
#define THR2_ 0.81f          // 0.9^2
#define EPSV_ 1e-6f
#define LPB_ 32              // Hough locations per block (one row segment)
#define NBLK_ (HW_/LPB_)     // 600 blocks per batch image

typedef unsigned long long ull;

// ---------------- Kernel 1: per-class compaction (8 parallel blocks) ----------------
// Block (c, b) scans all voting pixels, keeps class c, writes float4(nx, ny,
// half2(xs,ys), depth) into fixed segment [c*CAP_, ...). Pad-to-32 zero-filled
// (nx=ny=0 -> dot=0 -> never inlier). Class 0 never votes; its block does inits.
__global__ __launch_bounds__(256) void k_prep(
    const int* __restrict__ labels, const int* __restrict__ masks,
    const float* __restrict__ vp,
    ull* __restrict__ best, unsigned* __restrict__ ctr,
    float4* __restrict__ arr4, int* __restrict__ nvalid)
{
    int c = blockIdx.x;
    int b = blockIdx.y;
    labels += (size_t)b * HW_;
    masks  += (size_t)b * HW_;
    vp     += (size_t)b * 3 * NC_ * HW_;
    float4* a4 = arr4 + (size_t)b * PADCAP_ + (size_t)c * CAP_;

    __shared__ int s_pos;
    int t = threadIdx.x;
    if (t == 0) s_pos = 0;
    __syncthreads();

    if (c > 0) {
        for (int p = t; p < P_; p += 256) {
            int idx = p * SKIP_;
            if (masks[idx] > 0 && labels[idx] == c) {
                float xs = (float)(idx % W_);
                float ys = (float)(idx / W_);
                float vx = vp[(c*3 + 0)*HW_ + idx];
                float vy = vp[(c*3 + 1)*HW_ + idx];
                float vz = vp[(c*3 + 2)*HW_ + idx];
                float nrm = sqrtf(vx*vx + vy*vy) + EPSV_;
                float nx = vx / nrm, ny = vy / nrm;
                float depth = expf(vz);
                unsigned hx = __half_as_ushort(__float2half_rn(xs));  // exact: ints < 2048
                unsigned hy = __half_as_ushort(__float2half_rn(ys));
                int pos = atomicAdd(&s_pos, 1);
                if (pos < CAP_)
                    a4[pos] = make_float4(nx, ny, __uint_as_float(hx | (hy << 16)), depth);
            }
        }
    }
    __syncthreads();
    int cnt = s_pos;
    int used = cnt < CAP_ ? cnt : CAP_;
    if (t == 0) nvalid[b*NC_ + c] = cnt;           // true count (score denominator)
    // zero the pad tail so staged pads never vote
    int end = (used + 31) & ~31;
    for (int i = used + t; i < end; i += 256)
        a4[i] = make_float4(0.f, 0.f, 0.f, 0.f);
    if (c == 0) {
        if (t < NC_) best[b*NC_ + t] = 0ULL;       // init for atomicMax
        if (b == 0 && t == 0) *ctr = 0u;           // last-block counter
    }
}

// ---------------- Kernel 2: Hough voting + fused finalize ----------------
// grid (NBLK_, B), block 256. Block covers 32 consecutive L (one row chunk):
// thread t: chunk = t&31 (pixel strip), lgrp = t>>5; each thread evaluates
// 4 consecutive L per pixel read (dy/dy2/t1 shared -> ~49 VALU per ds_read_b128).
__global__ __launch_bounds__(256) void k_vote(
    const float4* __restrict__ arr4, const int* __restrict__ nvalid,
    ull* __restrict__ best, unsigned* __restrict__ ctr,
    const float* __restrict__ extents, const float* __restrict__ poses,
    const float* __restrict__ meta, float* __restrict__ out, int B)
{
    int b = blockIdx.y;
    const float4* a4 = arr4 + (size_t)b * PADCAP_;

    __shared__ float4 s_a[PADCAP_];   // 40960 B
    __shared__ int s_end[NC_];
    __shared__ ull s_best[NC_];
    __shared__ int s_last;

    int t = threadIdx.x;
    if (t < NC_) {
        int cnt = nvalid[b*NC_ + t];
        if (cnt > CAP_) cnt = CAP_;
        s_end[t] = t*CAP_ + ((cnt + 31) & ~31);
        s_best[t] = 0ULL;
    }
    __syncthreads();
    // stage only used (padded) segments
    for (int c = 1; c < NC_; ++c)
        for (int i = c*CAP_ + t; i < s_end[c]; i += 256) s_a[i] = a4[i];
    __syncthreads();

    int chunk = t & 31;
    int lgrp  = t >> 5;
    int L0 = blockIdx.x * LPB_;           // row-aligned: 160 % 32 == 0
    float gy  = (float)(L0 / W_);         // uniform over block
    int   xi0 = (L0 % W_) + lgrp * 4;
    float gx0 = (float)xi0;

    for (int c = 0; c < NC_; ++c) {
        int jend = s_end[c];
        int cc0 = 0, cc1 = 0, cc2 = 0, cc3 = 0;
        float dd0 = 0.f, dd1 = 0.f, dd2 = 0.f, dd3 = 0.f;
        for (int j = c*CAP_ + chunk; j < jend; j += 32) {
            float4 a = s_a[j];
            unsigned u = __float_as_uint(a.z);
            float xs = __half2float(__ushort_as_half((unsigned short)(u & 0xffffu)));
            float ys = __half2float(__ushort_as_half((unsigned short)(u >> 16)));
            float dy  = gy - ys;
            float t1  = dy * a.y;
            float dy2 = dy * dy;
            float dx0 = gx0 - xs;         // integer-valued: exact
            float dx1 = dx0 + 1.f, dx2 = dx0 + 2.f, dx3 = dx0 + 3.f;
            float o0 = fmaf(dx0, a.x, t1), q0 = fmaf(dx0, dx0, dy2);
            float o1 = fmaf(dx1, a.x, t1), q1 = fmaf(dx1, dx1, dy2);
            float o2 = fmaf(dx2, a.x, t1), q2 = fmaf(dx2, dx2, dy2);
            float o3 = fmaf(dx3, a.x, t1), q3 = fmaf(dx3, dx3, dy2);
            bool i0 = (o0 > 0.f) && (o0*o0 > THR2_*q0);
            bool i1 = (o1 > 0.f) && (o1*o1 > THR2_*q1);
            bool i2 = (o2 > 0.f) && (o2*o2 > THR2_*q2);
            bool i3 = (o3 > 0.f) && (o3*o3 > THR2_*q3);
            cc0 += i0; dd0 += i0 ? a.w : 0.f;
            cc1 += i1; dd1 += i1 ? a.w : 0.f;
            cc2 += i2; dd2 += i2 ? a.w : 0.f;
            cc3 += i3; dd3 += i3 ? a.w : 0.f;
        }
        // sum partial counts across the 32 pixel-chunks (lanes sharing lgrp)
        #pragma unroll
        for (int s = 1; s < 32; s <<= 1) {
            cc0 += __shfl_xor(cc0, s); dd0 += __shfl_xor(dd0, s);
            cc1 += __shfl_xor(cc1, s); dd1 += __shfl_xor(dd1, s);
            cc2 += __shfl_xor(cc2, s); dd2 += __shfl_xor(dd2, s);
            cc3 += __shfl_xor(cc3, s); dd3 += __shfl_xor(dd3, s);
        }
        if (chunk == 0) {
            // key: votes (<=2400, 12 bits) << 15 | (HW-1-L): max == argmax, lowest-L tiebreak
            int Lw = L0 + lgrp * 4;
            ull p0 = ((ull)(((unsigned)cc0 << 15) | (unsigned)(HW_-1 - Lw    )) << 32) | (ull)__float_as_uint(dd0);
            ull p1 = ((ull)(((unsigned)cc1 << 15) | (unsigned)(HW_-1 - Lw - 1)) << 32) | (ull)__float_as_uint(dd1);
            ull p2 = ((ull)(((unsigned)cc2 << 15) | (unsigned)(HW_-1 - Lw - 2)) << 32) | (ull)__float_as_uint(dd2);
            ull p3 = ((ull)(((unsigned)cc3 << 15) | (unsigned)(HW_-1 - Lw - 3)) << 32) | (ull)__float_as_uint(dd3);
            ull pk = p0 > p1 ? p0 : p1;
            ull pq = p2 > p3 ? p2 : p3;
            pk = pk > pq ? pk : pq;
            atomicMax(&s_best[c], pk);
        }
    }
    __syncthreads();
    if (t < NC_) atomicMax(&best[b*NC_ + t], s_best[t]);
    __syncthreads();

    // ---- last block finalizes boxes + poses ----
    if (t == 0) {
        __threadfence();
        unsigned r = atomicAdd(ctr, 1u);
        s_last = (r == (unsigned)(gridDim.x * gridDim.y) - 1u) ? 1 : 0;
    }
    __syncthreads();
    if (s_last) {
        for (int i = t; i < B * NC_; i += 256) {
            int bb = i / NC_, c = i % NC_;
            ull pk = atomicMax(&best[i], 0ULL);   // coherent device-scope read
            unsigned key = (unsigned)(pk >> 32);
            int Lw = (HW_ - 1) - (int)(key & 0x7FFFu);
            float vmax = (float)(key >> 15);
            float dsum = __uint_as_float((unsigned)(pk & 0xFFFFFFFFull));
            float nv = (float)nvalid[i];
            float dbar = dsum / fmaxf(vmax, 1.0f);
            float cx = (float)(Lw % W_), cy = (float)(Lw / W_);
            float fx = meta[bb*9 + 0], px = meta[bb*9 + 2];
            float fy = meta[bb*9 + 4], py = meta[bb*9 + 5];
            float e0 = extents[c*3 + 0], e1 = extents[c*3 + 1], e2 = extents[c*3 + 2];
            float diag = sqrtf(e0*e0 + e1*e1 + e2*e2);
            float safe_d = fmaxf(dbar, EPSV_);
            float bw = diag * fx / safe_d;
            float bh = diag * fy / safe_d;
            float score = vmax / fmaxf(nv, 1.0f);

            float* ob = out + (size_t)i * 7;
            ob[0] = (float)bb;
            ob[1] = (float)c;
            ob[2] = cx - bw * 0.5f;
            ob[3] = cy - bh * 0.5f;
            ob[4] = cx + bw * 0.5f;
            ob[5] = cy + bh * 0.5f;
            ob[6] = score;

            float* op = out + (size_t)B * NC_ * 7 + (size_t)i * 7;
            op[0] = poses[i*7 + 0];
            op[1] = poses[i*7 + 1];
            op[2] = poses[i*7 + 2];
            op[3] = poses[i*7 + 3];
            op[4] = (cx - px) * dbar / fmaxf(fx, EPSV_);
            op[5] = (cy - py) * dbar / fmaxf(fy, EPSV_);
            op[6] = dbar;
        }
    }
}

extern "C" void kernel_launch(void* const* d_in, const int* in_sizes, int n_in,
                              void* d_out, int out_size, void* d_ws, size_t ws_size,
                              hipStream_t stream)
{
    const int*   labels  = (const int*)d_in[0];
    const int*   masks   = (const int*)d_in[1];
    const float* vp      = (const float*)d_in[2];
    const float* extents = (const float*)d_in[3];
    const float* poses   = (const float*)d_in[4];
    const float* meta    = (const float*)d_in[5];
    int B = in_sizes[0] / HW_;

    // workspace layout (16B-aligned first)
    float4*   arr4   = (float4*)d_ws;                           // B*PADCAP_ float4
    ull*      best   = (ull*)(arr4 + (size_t)B * PADCAP_);      // B*NC ull
    int*      nvalid = (int*)(best + (size_t)B * NC_);          // B*NC int
    unsigned* ctr    = (unsigned*)(nvalid + (size_t)B * NC_);   // 1
    float*    out    = (float*)d_out;

    k_prep<<<dim3(NC_, B), 256, 0, stream>>>(labels, masks, vp, best, ctr, arr4, nvalid);
    k_vote<<<dim3(NBLK_, B), 256, 0, stream>>>(arr4, nvalid, best, ctr,
                                               extents, poses, meta, out, B);
}